// Round 15
// baseline (398.580 us; speedup 1.0000x reference)
//
#include <hip/hip_runtime.h>
#include <hip/hip_bf16.h>
#include <hip/hip_fp8.h>
#include <cstdint>
#include <cstddef>

// Problem dims
#define M_ROWS   4096     // B*T
#define N_VOCAB  32000    // V
#define K_DIM    512      // D
#define S_DIM    400
#define CV_DIM   600
#define OUT_PITCH 32600   // V + CV
#define PAD_IDX  1

typedef __attribute__((ext_vector_type(8))) short short8;
typedef __attribute__((ext_vector_type(8))) unsigned short ushort8;
typedef __attribute__((ext_vector_type(4))) float f32x4;
typedef long long i64;

// ws layout (fp8 inputs + bf16 exp intermediate) — R13 layout
#define W8_OFF   0ull                        // W fp8: 16,384,000 B
#define H8_OFF   16384000ull                 // hidden fp8: 2,097,152 B
#define COPYG_OFF 18481152ull
#define RSUM_OFF  18497536ull
#define SSCALE_OFF 18513920ull
#define SRCID_OFF 18530304ull                // 51,200 B
#define EB_OFF    18581504ull                // bf16 exp intermediate: 262,144,000 B
#define WS_NEED   (EB_OFF + 262144000ull)

__device__ inline void gload_lds16(const void* g, void* l) {
  __builtin_amdgcn_global_load_lds(
      (const __attribute__((address_space(1))) unsigned int*)g,
      (__attribute__((address_space(3))) unsigned int*)l, 16, 0, 0);
}

__device__ inline unsigned short f32_to_bf16_rn(float f) {
  unsigned u = __float_as_uint(f);
  u += 0x7FFFu + ((u >> 16) & 1u);
  return (unsigned short)(u >> 16);
}
__device__ inline float bf16_to_f32(unsigned short h) {
  return __uint_as_float((unsigned)h << 16);
}
__device__ inline unsigned f32_to_fp8(float f) {
  __hip_fp8_e4m3 q(f);
  return (unsigned)(unsigned char)q.__x;
}

// ---------- K1a: fp32 -> fp8 conversion (W), packed 4/thread ----------
__global__ void cvt8_kernel(const float4* __restrict__ in, unsigned* __restrict__ out, unsigned n4) {
  unsigned stride = gridDim.x * blockDim.x;
  for (unsigned i = blockIdx.x * blockDim.x + threadIdx.x; i < n4; i += stride) {
    float4 v = in[i];
    out[i] = f32_to_fp8(v.x) | (f32_to_fp8(v.y) << 8)
           | (f32_to_fp8(v.z) << 16) | (f32_to_fp8(v.w) << 24);
  }
}

// ---------- K1b: copy gate + hidden->fp8 (fused; one wave per row) ----------
__global__ void copygate_cvt_kernel(const float* __restrict__ hidden,
                                    const float* __restrict__ w_copy,
                                    const float* __restrict__ b_copy,
                                    float* __restrict__ copyg,
                                    unsigned char* __restrict__ H8) {
  unsigned gw = (blockIdx.x * blockDim.x + threadIdx.x) >> 6;   // row
  unsigned lane = threadIdx.x & 63u;
  if (gw >= M_ROWS) return;
  const float4* h4 = (const float4*)(hidden + (size_t)gw * K_DIM);
  const float4* w4 = (const float4*)w_copy;
  float4 a0 = h4[lane * 2 + 0], w0 = w4[lane * 2 + 0];
  float4 a1 = h4[lane * 2 + 1], w1 = w4[lane * 2 + 1];
  float dot = a0.x * w0.x + a0.y * w0.y + a0.z * w0.z + a0.w * w0.w
            + a1.x * w1.x + a1.y * w1.y + a1.z * w1.z + a1.w * w1.w;
  unsigned lo = f32_to_fp8(a0.x) | (f32_to_fp8(a0.y) << 8)
              | (f32_to_fp8(a0.z) << 16) | (f32_to_fp8(a0.w) << 24);
  unsigned hi = f32_to_fp8(a1.x) | (f32_to_fp8(a1.y) << 8)
              | (f32_to_fp8(a1.z) << 16) | (f32_to_fp8(a1.w) << 24);
  uint2 pk; pk.x = lo; pk.y = hi;
  *(uint2*)(H8 + (size_t)gw * K_DIM + lane * 8u) = pk;
  #pragma unroll
  for (int mask = 1; mask < 64; mask <<= 1) dot += __shfl_xor(dot, mask);
  if (lane == 0) copyg[gw] = 1.f / (1.f + __expf(-(dot + b_copy[0])));
}

// ---------- K1c: recover src_ids from one-hot src_map ----------
__global__ void srcids_kernel(const float* __restrict__ src_map, int* __restrict__ src_ids) {
  unsigned pos = (blockIdx.x * blockDim.x + threadIdx.x) >> 6;
  unsigned lane = threadIdx.x & 63u;
  if (pos >= 32 * S_DIM) return;
  const float* row = src_map + (size_t)pos * CV_DIM;
  int found = 1 << 30;
  for (int v = lane; v < CV_DIM; v += 64)
    if (row[v] > 0.5f) found = v;
  #pragma unroll
  for (int mask = 1; mask < 64; mask <<= 1) {
    int o = __shfl_xor(found, mask);
    found = found < o ? found : o;
  }
  if (lane == 0) src_ids[pos] = found;
}

// ---------- K2: 256x128 fp8 MFMA GEMM, BK=64 double-buffered 2-phase ----------
// T3 minimum 2-phase (m248v2 recipe): STAGE(t+1) issued BEFORE compute(t);
// one __syncthreads per K-step (vmcnt drain overlaps the 32 MFMAs).
// 2 x 24 KB buffers = 48 KB LDS (same as R13) -> 2 blocks/CU preserved.
// Rows = 64 B = 4 x 16B chunks; swizzle chunk ^= row&3 (2 lanes/bank = free).
// Swapped operands: lane holds 4 consecutive output cols -> ushort4 stores.
template<int BF16OUT>
__global__ __launch_bounds__(512, 2)
void gemm_exp_kernel(const unsigned char* __restrict__ A,
                     const unsigned char* __restrict__ B,
                     const float* __restrict__ bias,
                     float* __restrict__ out,
                     unsigned short* __restrict__ Eb,
                     float* __restrict__ row_sum) {
  __shared__ unsigned char smem[49152];      // 2 buffers: [As 16K | Bs 8K] each

  unsigned bid = blockIdx.x;
  // reuse-aware bijective map over 4000 blocks (16 mt x 250 nt)
  unsigned xcd = bid & 7u, local = bid >> 3;      // local 0..499
  unsigned slab = xcd >> 1, half = xcd & 1u;
  unsigned nt = half * 125u + (local >> 2);
  unsigned mt = slab * 4u + (local & 3u);
  unsigned m0 = mt * 256u, n0 = nt * 128u;

  unsigned tid = threadIdx.x;
  unsigned lane = tid & 63u;
  unsigned wid = tid >> 6;
  unsigned wm = wid >> 1, wn = wid & 1u;     // 4 x 2 wave grid, 64x64 per wave
  unsigned lr = lane >> 4, lc = lane & 15u;

  // staging: A 1024 16B-units (2/thread), B 512 (1/thread);
  // unit u -> row u>>2, lds chunk u&3, source chunk (u&3)^(row&3)
  const unsigned char* Asrc[2];
  const unsigned char* Bsrc0;
  unsigned dstA[2], dstB0;
  #pragma unroll
  for (unsigned i = 0; i < 2; ++i) {
    unsigned u = i * 512u + tid;
    unsigned rr = u >> 2;                        // 0..255
    unsigned ch = (u & 3u) ^ (rr & 3u);
    dstA[i] = u * 16u;
    Asrc[i] = A + (size_t)(m0 + rr) * K_DIM + ch * 16u;
  }
  {
    unsigned u = tid;
    unsigned rr = u >> 2;                        // 0..127
    unsigned ch = (u & 3u) ^ (rr & 3u);
    dstB0 = u * 16u;
    Bsrc0 = B + (size_t)(n0 + rr) * K_DIM + ch * 16u;
  }
  // fragment read bases (row byte base within region + swizzle key)
  unsigned abase[4], akey[4], bbase[4], bkey[4];
  #pragma unroll
  for (int m = 0; m < 4; ++m) {
    unsigned r = wm * 64u + m * 16u + lc;
    abase[m] = r * 64u; akey[m] = r & 3u;
  }
  #pragma unroll
  for (int n = 0; n < 4; ++n) {
    unsigned r = wn * 64u + n * 16u + lc;
    bbase[n] = 16384u + r * 64u; bkey[n] = r & 3u;
  }
  const unsigned hsel = (lr & 1u) * 8u;          // 8B half within 16B chunk

  f32x4 acc[4][4] = {};

  // prologue: stage tile 0
  {
    unsigned char* base = smem;
    gload_lds16(Asrc[0], base + dstA[0]);
    gload_lds16(Asrc[1], base + dstA[1]);
    gload_lds16(Bsrc0, base + 16384u + dstB0);
  }
  __syncthreads();

  for (unsigned kt = 0; kt < 8; ++kt) {          // BK=64: 8 K-steps
    unsigned buf = kt & 1u;
    if (kt < 7) {                                // stage t+1 BEFORE compute(t)
      unsigned k0 = (kt + 1u) * 64u;
      unsigned char* base = smem + (buf ^ 1u) * 24576u;
      gload_lds16(Asrc[0] + k0, base + dstA[0]);
      gload_lds16(Asrc[1] + k0, base + dstA[1]);
      gload_lds16(Bsrc0 + k0, base + 16384u + dstB0);
    }
    const unsigned char* cbase = smem + buf * 24576u;
    #pragma unroll
    for (unsigned ks = 0; ks < 2; ++ks) {        // k = ks*32 .. +32
      unsigned h = ks * 2u + (lr >> 1);          // 16B chunk index 0..3
      i64 av[4], bv[4];
      #pragma unroll
      for (int m = 0; m < 4; ++m)
        av[m] = *(const i64*)(cbase + abase[m] + ((h ^ akey[m]) * 16u) + hsel);
      #pragma unroll
      for (int n = 0; n < 4; ++n)
        bv[n] = *(const i64*)(cbase + bbase[n] + ((h ^ bkey[n]) * 16u) + hsel);
      #pragma unroll
      for (int m = 0; m < 4; ++m)
        #pragma unroll
        for (int n = 0; n < 4; ++n)
          acc[m][n] = __builtin_amdgcn_mfma_f32_16x16x32_fp8_fp8(bv[n], av[m],
                                                                 acc[m][n], 0, 0, 0);
    }
    __syncthreads();   // drains vmcnt (stage landed during MFMAs) + read-retire
  }

  // epilogue: acc[m][n][j] = logit(row = m0+wm*64+m*16+lc, col = n0+wn*64+n*16+lr*4+j)
  float4 bv4[4];
  #pragma unroll
  for (int n = 0; n < 4; ++n)
    bv4[n] = *(const float4*)&bias[n0 + wn * 64u + n * 16u + lr * 4u];

  if (BF16OUT) {
    #pragma unroll
    for (int m = 0; m < 4; ++m) {
      unsigned grow = m0 + wm * 64u + m * 16u + lc;
      unsigned short* rowp = Eb + (size_t)grow * N_VOCAB;
      #pragma unroll
      for (int n = 0; n < 4; ++n) {
        unsigned gcol = n0 + wn * 64u + n * 16u + lr * 4u;
        float e0 = (gcol + 0u == PAD_IDX) ? 0.f : __expf(acc[m][n][0] + bv4[n].x);
        float e1 = (gcol + 1u == PAD_IDX) ? 0.f : __expf(acc[m][n][1] + bv4[n].y);
        float e2 = (gcol + 2u == PAD_IDX) ? 0.f : __expf(acc[m][n][2] + bv4[n].z);
        float e3 = (gcol + 3u == PAD_IDX) ? 0.f : __expf(acc[m][n][3] + bv4[n].w);
        ushort4 o;
        o.x = f32_to_bf16_rn(e0); o.y = f32_to_bf16_rn(e1);
        o.z = f32_to_bf16_rn(e2); o.w = f32_to_bf16_rn(e3);
        *(ushort4*)(rowp + gcol) = o;
      }
    }
  } else {
    // fallback: fp32 float4 stores + atomic row sums
    #pragma unroll
    for (int m = 0; m < 4; ++m) {
      unsigned grow = m0 + wm * 64u + m * 16u + lc;
      float rs = 0.f;
      #pragma unroll
      for (int n = 0; n < 4; ++n) {
        unsigned gcol = n0 + wn * 64u + n * 16u + lr * 4u;
        float4 e;
        e.x = (gcol + 0u == PAD_IDX) ? 0.f : __expf(acc[m][n][0] + bv4[n].x);
        e.y = (gcol + 1u == PAD_IDX) ? 0.f : __expf(acc[m][n][1] + bv4[n].y);
        e.z = (gcol + 2u == PAD_IDX) ? 0.f : __expf(acc[m][n][2] + bv4[n].z);
        e.w = (gcol + 3u == PAD_IDX) ? 0.f : __expf(acc[m][n][3] + bv4[n].w);
        *(float4*)(out + (size_t)grow * OUT_PITCH + gcol) = e;
        rs += e.x + e.y + e.z + e.w;
      }
      rs += __shfl_xor(rs, 16);
      rs += __shfl_xor(rs, 32);
      if (lr == 0) atomicAdd(&row_sum[grow], rs);
    }
  }
}

// ---------- K3: fused per-row sum + scale + copy-branch scatter ----------
// One block per row. Row (62.5 KB bf16) to registers, block-reduce sum,
// scale+store fp32 main region; copy branch scattered via LDS into the
// same row's extended-vocab region. No atomics on global.
__global__ __launch_bounds__(256)
void norm_scale_copy_kernel(const unsigned short* __restrict__ Eb,
                            const float* __restrict__ copyg,
                            const float* __restrict__ attn,
                            const int* __restrict__ src_ids,
                            float* __restrict__ out) {
  unsigned r = blockIdx.x;
  unsigned tid = threadIdx.x;
  __shared__ float cp[CV_DIM];
  __shared__ float wsum[4];
  for (unsigned v2 = tid; v2 < CV_DIM; v2 += 256) cp[v2] = 0.f;

  const ushort8* src = (const ushort8*)(Eb + (size_t)r * N_VOCAB);   // 4000 chunks
  ushort8 v[16];
  float lsum = 0.f;
  #pragma unroll
  for (int i = 0; i < 16; ++i) {
    unsigned c = (unsigned)i * 256u + tid;
    if (c < 4000u) {
      v[i] = src[c];
      #pragma unroll
      for (int k = 0; k < 8; ++k) lsum += bf16_to_f32(v[i][k]);
    }
  }
  #pragma unroll
  for (int mask = 1; mask < 64; mask <<= 1) lsum += __shfl_xor(lsum, mask);
  if ((tid & 63u) == 0) wsum[tid >> 6] = lsum;
  __syncthreads();                 // wsum ready; cp zeroed

  float g = copyg[r];
  float s = (1.f - g) / (wsum[0] + wsum[1] + wsum[2] + wsum[3]);

  // copy-branch scatter into LDS (row's batch shares src_ids)
  unsigned batch = r >> 7;
  for (unsigned sp = tid; sp < S_DIM; sp += 256) {
    float a = attn[(size_t)r * S_DIM + sp] * g;
    atomicAdd(&cp[src_ids[batch * S_DIM + sp]], a);
  }

  // main region scale + store (from registers)
  float* dst = out + (size_t)r * OUT_PITCH;
  #pragma unroll
  for (int i = 0; i < 16; ++i) {
    unsigned c = (unsigned)i * 256u + tid;
    if (c < 4000u) {
      float4 lo, hi;
      lo.x = bf16_to_f32(v[i][0]) * s; lo.y = bf16_to_f32(v[i][1]) * s;
      lo.z = bf16_to_f32(v[i][2]) * s; lo.w = bf16_to_f32(v[i][3]) * s;
      hi.x = bf16_to_f32(v[i][4]) * s; hi.y = bf16_to_f32(v[i][5]) * s;
      hi.z = bf16_to_f32(v[i][6]) * s; hi.w = bf16_to_f32(v[i][7]) * s;
      float4* o = (float4*)(dst + c * 8u);
      o[0] = lo; o[1] = hi;
    }
  }
  __syncthreads();                 // scatter complete
  for (unsigned v2 = tid; v2 < CV_DIM; v2 += 256)
    dst[N_VOCAB + v2] = cp[v2];
}

// ---------- fallback-path kernels ----------
__global__ void finalize_kernel(const float* __restrict__ row_sum, const float* __restrict__ copyg,
                                float* __restrict__ sscale) {
  unsigned r = blockIdx.x * blockDim.x + threadIdx.x;
  if (r < M_ROWS) sscale[r] = (1.f - copyg[r]) / row_sum[r];
}

__global__ void scale_kernel(float4* __restrict__ out, const float* __restrict__ sscale) {
  const unsigned total = M_ROWS * (N_VOCAB / 4);
  unsigned stride = gridDim.x * blockDim.x;
  for (unsigned i = blockIdx.x * blockDim.x + threadIdx.x; i < total; i += stride) {
    unsigned r = i / (N_VOCAB / 4);
    unsigned c = i % (N_VOCAB / 4);
    float s = sscale[r];
    float4 v = out[(size_t)r * (OUT_PITCH / 4) + c];
    v.x *= s; v.y *= s; v.z *= s; v.w *= s;
    out[(size_t)r * (OUT_PITCH / 4) + c] = v;
  }
}

__global__ void copyprob_kernel(const float* __restrict__ attn, const int* __restrict__ src_ids,
                                const float* __restrict__ copyg, float* __restrict__ out) {
  unsigned r = blockIdx.x;
  unsigned tid = threadIdx.x;
  __shared__ float cp[CV_DIM];
  for (unsigned v = tid; v < CV_DIM; v += 128) cp[v] = 0.f;
  __syncthreads();
  unsigned batch = r >> 7;
  float g = copyg[r];
  for (unsigned s = tid; s < S_DIM; s += 128) {
    float a = attn[(size_t)r * S_DIM + s] * g;
    atomicAdd(&cp[src_ids[batch * S_DIM + s]], a);
  }
  __syncthreads();
  for (unsigned v = tid; v < CV_DIM; v += 128)
    out[(size_t)r * OUT_PITCH + N_VOCAB + v] = cp[v];
}

extern "C" void kernel_launch(void* const* d_in, const int* in_sizes, int n_in,
                              void* d_out, int out_size, void* d_ws, size_t ws_size,
                              hipStream_t stream) {
  const float* hidden    = (const float*)d_in[0];
  const float* copy_attn = (const float*)d_in[1];
  const float* src_map   = (const float*)d_in[2];
  const float* W         = (const float*)d_in[3];
  const float* bias      = (const float*)d_in[4];
  const float* w_copy    = (const float*)d_in[5];
  const float* b_copy    = (const float*)d_in[6];
  float* out = (float*)d_out;

  char* ws = (char*)d_ws;
  unsigned char* W8 = (unsigned char*)(ws + W8_OFF);
  unsigned char* H8 = (unsigned char*)(ws + H8_OFF);
  float* copyg   = (float*)(ws + COPYG_OFF);
  float* row_sum = (float*)(ws + RSUM_OFF);
  float* sscale  = (float*)(ws + SSCALE_OFF);
  int*   src_ids = (int*)(ws + SRCID_OFF);
  unsigned short* Eb = (unsigned short*)(ws + EB_OFF);

  const bool bf16_path = (ws_size >= WS_NEED);

  cvt8_kernel<<<2048, 256, 0, stream>>>((const float4*)W, (unsigned*)W8,
                                        (unsigned)(N_VOCAB * K_DIM / 4));
  copygate_cvt_kernel<<<M_ROWS / 4, 256, 0, stream>>>(hidden, w_copy, b_copy, copyg, H8);
  srcids_kernel<<<(32 * S_DIM) / 4, 256, 0, stream>>>(src_map, src_ids);

  // main GEMM: 16 x 250 tiles of 256x128, 512 threads, 2 blocks/CU
  if (bf16_path) {
    gemm_exp_kernel<1><<<(M_ROWS / 256) * (N_VOCAB / 128), 512, 0, stream>>>(
        H8, W8, bias, out, Eb, row_sum);
    norm_scale_copy_kernel<<<M_ROWS, 256, 0, stream>>>(Eb, copyg, copy_attn, src_ids, out);
  } else {
    hipMemsetAsync(row_sum, 0, M_ROWS * sizeof(float), stream);
    gemm_exp_kernel<0><<<(M_ROWS / 256) * (N_VOCAB / 128), 512, 0, stream>>>(
        H8, W8, bias, out, Eb, row_sum);
    finalize_kernel<<<(M_ROWS + 255) / 256, 256, 0, stream>>>(row_sum, copyg, sscale);
    scale_kernel<<<4096, 256, 0, stream>>>((float4*)out, sscale);
    copyprob_kernel<<<M_ROWS, 128, 0, stream>>>(copy_attn, src_ids, copyg, out);
  }
}

// Round 16
// 364.453 us; speedup vs baseline: 1.0936x; 1.0936x over previous
//
#include <hip/hip_runtime.h>
#include <hip/hip_bf16.h>
#include <hip/hip_fp8.h>
#include <cstdint>
#include <cstddef>

// Problem dims
#define M_ROWS   4096     // B*T
#define N_VOCAB  32000    // V
#define K_DIM    512      // D
#define S_DIM    400
#define CV_DIM   600
#define OUT_PITCH 32600   // V + CV
#define PAD_IDX  1

typedef __attribute__((ext_vector_type(8))) short short8;
typedef __attribute__((ext_vector_type(8))) unsigned short ushort8;
typedef __attribute__((ext_vector_type(4))) float f32x4;
typedef long long i64;

// ws layout (fp8 inputs + bf16 exp intermediate) — R13 layout
#define W8_OFF   0ull                        // W fp8: 16,384,000 B
#define H8_OFF   16384000ull                 // hidden fp8: 2,097,152 B
#define COPYG_OFF 18481152ull
#define RSUM_OFF  18497536ull
#define SSCALE_OFF 18513920ull
#define SRCID_OFF 18530304ull                // 51,200 B
#define EB_OFF    18581504ull                // bf16 exp intermediate: 262,144,000 B
#define WS_NEED   (EB_OFF + 262144000ull)

__device__ inline void gload_lds16(const void* g, void* l) {
  __builtin_amdgcn_global_load_lds(
      (const __attribute__((address_space(1))) unsigned int*)g,
      (__attribute__((address_space(3))) unsigned int*)l, 16, 0, 0);
}

__device__ inline unsigned short f32_to_bf16_rn(float f) {
  unsigned u = __float_as_uint(f);
  u += 0x7FFFu + ((u >> 16) & 1u);
  return (unsigned short)(u >> 16);
}
__device__ inline float bf16_to_f32(unsigned short h) {
  return __uint_as_float((unsigned)h << 16);
}
__device__ inline unsigned f32_to_fp8(float f) {
  __hip_fp8_e4m3 q(f);
  return (unsigned)(unsigned char)q.__x;
}

// ---------- K1a: fp32 -> fp8 conversion (W), packed 4/thread ----------
__global__ void cvt8_kernel(const float4* __restrict__ in, unsigned* __restrict__ out, unsigned n4) {
  unsigned stride = gridDim.x * blockDim.x;
  for (unsigned i = blockIdx.x * blockDim.x + threadIdx.x; i < n4; i += stride) {
    float4 v = in[i];
    out[i] = f32_to_fp8(v.x) | (f32_to_fp8(v.y) << 8)
           | (f32_to_fp8(v.z) << 16) | (f32_to_fp8(v.w) << 24);
  }
}

// ---------- K1b: copy gate + hidden->fp8 (fused; one wave per row) ----------
__global__ void copygate_cvt_kernel(const float* __restrict__ hidden,
                                    const float* __restrict__ w_copy,
                                    const float* __restrict__ b_copy,
                                    float* __restrict__ copyg,
                                    unsigned char* __restrict__ H8) {
  unsigned gw = (blockIdx.x * blockDim.x + threadIdx.x) >> 6;   // row
  unsigned lane = threadIdx.x & 63u;
  if (gw >= M_ROWS) return;
  const float4* h4 = (const float4*)(hidden + (size_t)gw * K_DIM);
  const float4* w4 = (const float4*)w_copy;
  float4 a0 = h4[lane * 2 + 0], w0 = w4[lane * 2 + 0];
  float4 a1 = h4[lane * 2 + 1], w1 = w4[lane * 2 + 1];
  float dot = a0.x * w0.x + a0.y * w0.y + a0.z * w0.z + a0.w * w0.w
            + a1.x * w1.x + a1.y * w1.y + a1.z * w1.z + a1.w * w1.w;
  unsigned lo = f32_to_fp8(a0.x) | (f32_to_fp8(a0.y) << 8)
              | (f32_to_fp8(a0.z) << 16) | (f32_to_fp8(a0.w) << 24);
  unsigned hi = f32_to_fp8(a1.x) | (f32_to_fp8(a1.y) << 8)
              | (f32_to_fp8(a1.z) << 16) | (f32_to_fp8(a1.w) << 24);
  uint2 pk; pk.x = lo; pk.y = hi;
  *(uint2*)(H8 + (size_t)gw * K_DIM + lane * 8u) = pk;
  #pragma unroll
  for (int mask = 1; mask < 64; mask <<= 1) dot += __shfl_xor(dot, mask);
  if (lane == 0) copyg[gw] = 1.f / (1.f + __expf(-(dot + b_copy[0])));
}

// ---------- K1c: recover src_ids from one-hot src_map ----------
__global__ void srcids_kernel(const float* __restrict__ src_map, int* __restrict__ src_ids) {
  unsigned pos = (blockIdx.x * blockDim.x + threadIdx.x) >> 6;
  unsigned lane = threadIdx.x & 63u;
  if (pos >= 32 * S_DIM) return;
  const float* row = src_map + (size_t)pos * CV_DIM;
  int found = 1 << 30;
  for (int v = lane; v < CV_DIM; v += 64)
    if (row[v] > 0.5f) found = v;
  #pragma unroll
  for (int mask = 1; mask < 64; mask <<= 1) {
    int o = __shfl_xor(found, mask);
    found = found < o ? found : o;
  }
  if (lane == 0) src_ids[pos] = found;
}

// ---------- K2: 256x128 fp8 MFMA GEMM, BK=128 + exp epilogue (bf16 out) ----------
// R13 structure (byte-for-byte): 8 waves (4M x 2N), 64x64/wave, BK=128 ->
// 4 K-steps, 48 KB LDS, XOR-(row&7) swizzle, 2 blocks/CU, reuse-aware XCD
// map, swapped operands -> register-direct ushort4 bf16 stores.
template<int BF16OUT>
__global__ __launch_bounds__(512, 2)
void gemm_exp_kernel(const unsigned char* __restrict__ A,
                     const unsigned char* __restrict__ B,
                     const float* __restrict__ bias,
                     float* __restrict__ out,
                     unsigned short* __restrict__ Eb,
                     float* __restrict__ row_sum) {
  __shared__ unsigned char smem[49152];      // As 32 KB | Bs 16 KB
  unsigned char* As = smem;
  unsigned char* Bs = smem + 32768;

  unsigned bid = blockIdx.x;
  // reuse-aware bijective map over 4000 blocks (16 mt x 250 nt)
  unsigned xcd = bid & 7u, local = bid >> 3;      // local 0..499
  unsigned slab = xcd >> 1, half = xcd & 1u;
  unsigned nt = half * 125u + (local >> 2);
  unsigned mt = slab * 4u + (local & 3u);
  unsigned m0 = mt * 256u, n0 = nt * 128u;

  unsigned tid = threadIdx.x;
  unsigned lane = tid & 63u;
  unsigned wid = tid >> 6;
  unsigned wm = wid >> 1, wn = wid & 1u;     // 4 x 2 wave grid, 64x64 per wave
  unsigned lr = lane >> 4, lc = lane & 15u;

  // staging: A 2048 16B-units, B 1024; unit u -> row u>>3, lds chunk u&7,
  // source chunk (u&7)^(row&7). Row = 128 fp8 = 128 B.
  const unsigned char* Asrc[4];
  const unsigned char* Bsrc[2];
  unsigned dstA[4], dstB[2];
  #pragma unroll
  for (unsigned i = 0; i < 4; ++i) {
    unsigned u = i * 512u + tid;
    unsigned rr = u >> 3;                        // 0..255
    unsigned ch = (u & 7u) ^ (rr & 7u);
    dstA[i] = u * 16u;
    Asrc[i] = A + (size_t)(m0 + rr) * K_DIM + ch * 16u;
  }
  #pragma unroll
  for (unsigned i = 0; i < 2; ++i) {
    unsigned u = i * 512u + tid;
    unsigned rr = u >> 3;                        // 0..127
    unsigned ch = (u & 7u) ^ (rr & 7u);
    dstB[i] = u * 16u;
    Bsrc[i] = B + (size_t)(n0 + rr) * K_DIM + ch * 16u;
  }
  // fragment read bases: row byte base + swizzle key
  unsigned abase[4], akey[4], bbase[4], bkey[4];
  #pragma unroll
  for (int m = 0; m < 4; ++m) {
    unsigned r = wm * 64u + m * 16u + lc;
    abase[m] = r * 128u; akey[m] = r & 7u;
  }
  #pragma unroll
  for (int n = 0; n < 4; ++n) {
    unsigned r = wn * 64u + n * 16u + lc;
    bbase[n] = r * 128u; bkey[n] = r & 7u;
  }
  const unsigned hsel = (lr & 1u) * 8u;          // 8B half within 16B chunk

  f32x4 acc[4][4] = {};

  for (unsigned kt = 0; kt < 4; ++kt) {          // BK=128: 4 K-steps only
    unsigned k0 = kt * 128u;
    #pragma unroll
    for (unsigned i = 0; i < 4; ++i)
      gload_lds16(Asrc[i] + k0, As + dstA[i]);
    #pragma unroll
    for (unsigned i = 0; i < 2; ++i)
      gload_lds16(Bsrc[i] + k0, Bs + dstB[i]);
    __syncthreads();   // compiler emits vmcnt(0) drain before barrier
    #pragma unroll
    for (unsigned ks = 0; ks < 4; ++ks) {        // k = ks*32 .. +32
      unsigned h = ks * 2u + (lr >> 1);          // 16B chunk index 0..7
      i64 av[4], bv[4];
      #pragma unroll
      for (int m = 0; m < 4; ++m)
        av[m] = *(const i64*)(As + abase[m] + ((h ^ akey[m]) * 16u) + hsel);
      #pragma unroll
      for (int n = 0; n < 4; ++n)
        bv[n] = *(const i64*)(Bs + bbase[n] + ((h ^ bkey[n]) * 16u) + hsel);
      #pragma unroll
      for (int m = 0; m < 4; ++m)
        #pragma unroll
        for (int n = 0; n < 4; ++n)
          acc[m][n] = __builtin_amdgcn_mfma_f32_16x16x32_fp8_fp8(bv[n], av[m],
                                                                 acc[m][n], 0, 0, 0);
    }
    __syncthreads();
  }

  // epilogue: acc[m][n][j] = logit(row = m0+wm*64+m*16+lc, col = n0+wn*64+n*16+lr*4+j)
  float4 bv4[4];
  #pragma unroll
  for (int n = 0; n < 4; ++n)
    bv4[n] = *(const float4*)&bias[n0 + wn * 64u + n * 16u + lr * 4u];

  if (BF16OUT) {
    #pragma unroll
    for (int m = 0; m < 4; ++m) {
      unsigned grow = m0 + wm * 64u + m * 16u + lc;
      unsigned short* rowp = Eb + (size_t)grow * N_VOCAB;
      #pragma unroll
      for (int n = 0; n < 4; ++n) {
        unsigned gcol = n0 + wn * 64u + n * 16u + lr * 4u;
        float e0 = (gcol + 0u == PAD_IDX) ? 0.f : __expf(acc[m][n][0] + bv4[n].x);
        float e1 = (gcol + 1u == PAD_IDX) ? 0.f : __expf(acc[m][n][1] + bv4[n].y);
        float e2 = (gcol + 2u == PAD_IDX) ? 0.f : __expf(acc[m][n][2] + bv4[n].z);
        float e3 = (gcol + 3u == PAD_IDX) ? 0.f : __expf(acc[m][n][3] + bv4[n].w);
        ushort4 o;
        o.x = f32_to_bf16_rn(e0); o.y = f32_to_bf16_rn(e1);
        o.z = f32_to_bf16_rn(e2); o.w = f32_to_bf16_rn(e3);
        *(ushort4*)(rowp + gcol) = o;
      }
    }
  } else {
    // fallback: fp32 float4 stores + atomic row sums
    #pragma unroll
    for (int m = 0; m < 4; ++m) {
      unsigned grow = m0 + wm * 64u + m * 16u + lc;
      float rs = 0.f;
      #pragma unroll
      for (int n = 0; n < 4; ++n) {
        unsigned gcol = n0 + wn * 64u + n * 16u + lr * 4u;
        float4 e;
        e.x = (gcol + 0u == PAD_IDX) ? 0.f : __expf(acc[m][n][0] + bv4[n].x);
        e.y = (gcol + 1u == PAD_IDX) ? 0.f : __expf(acc[m][n][1] + bv4[n].y);
        e.z = (gcol + 2u == PAD_IDX) ? 0.f : __expf(acc[m][n][2] + bv4[n].z);
        e.w = (gcol + 3u == PAD_IDX) ? 0.f : __expf(acc[m][n][3] + bv4[n].w);
        *(float4*)(out + (size_t)grow * OUT_PITCH + gcol) = e;
        rs += e.x + e.y + e.z + e.w;
      }
      rs += __shfl_xor(rs, 16);
      rs += __shfl_xor(rs, 32);
      if (lr == 0) atomicAdd(&row_sum[grow], rs);
    }
  }
}

// ---------- K3: fused per-row sum + scale + copy-branch scatter ----------
// (R15-proven correct.) One block per row. Row (62.5 KB bf16) to registers,
// block-reduce sum, scale+store fp32 main region; copy branch scattered via
// LDS into the same row's extended-vocab region. No global atomics.
__global__ __launch_bounds__(256)
void norm_scale_copy_kernel(const unsigned short* __restrict__ Eb,
                            const float* __restrict__ copyg,
                            const float* __restrict__ attn,
                            const int* __restrict__ src_ids,
                            float* __restrict__ out) {
  unsigned r = blockIdx.x;
  unsigned tid = threadIdx.x;
  __shared__ float cp[CV_DIM];
  __shared__ float wsum[4];
  for (unsigned v2 = tid; v2 < CV_DIM; v2 += 256) cp[v2] = 0.f;

  const ushort8* src = (const ushort8*)(Eb + (size_t)r * N_VOCAB);   // 4000 chunks
  ushort8 v[16];
  float lsum = 0.f;
  #pragma unroll
  for (int i = 0; i < 16; ++i) {
    unsigned c = (unsigned)i * 256u + tid;
    if (c < 4000u) {
      v[i] = src[c];
      #pragma unroll
      for (int k = 0; k < 8; ++k) lsum += bf16_to_f32(v[i][k]);
    }
  }
  #pragma unroll
  for (int mask = 1; mask < 64; mask <<= 1) lsum += __shfl_xor(lsum, mask);
  if ((tid & 63u) == 0) wsum[tid >> 6] = lsum;
  __syncthreads();                 // wsum ready; cp zeroed

  float g = copyg[r];
  float s = (1.f - g) / (wsum[0] + wsum[1] + wsum[2] + wsum[3]);

  // copy-branch scatter into LDS (row's batch shares src_ids)
  unsigned batch = r >> 7;
  for (unsigned sp = tid; sp < S_DIM; sp += 256) {
    float a = attn[(size_t)r * S_DIM + sp] * g;
    atomicAdd(&cp[src_ids[batch * S_DIM + sp]], a);
  }

  // main region scale + store (from registers)
  float* dst = out + (size_t)r * OUT_PITCH;
  #pragma unroll
  for (int i = 0; i < 16; ++i) {
    unsigned c = (unsigned)i * 256u + tid;
    if (c < 4000u) {
      float4 lo, hi;
      lo.x = bf16_to_f32(v[i][0]) * s; lo.y = bf16_to_f32(v[i][1]) * s;
      lo.z = bf16_to_f32(v[i][2]) * s; lo.w = bf16_to_f32(v[i][3]) * s;
      hi.x = bf16_to_f32(v[i][4]) * s; hi.y = bf16_to_f32(v[i][5]) * s;
      hi.z = bf16_to_f32(v[i][6]) * s; hi.w = bf16_to_f32(v[i][7]) * s;
      float4* o = (float4*)(dst + c * 8u);
      o[0] = lo; o[1] = hi;
    }
  }
  __syncthreads();                 // scatter complete
  for (unsigned v2 = tid; v2 < CV_DIM; v2 += 256)
    dst[N_VOCAB + v2] = cp[v2];
}

// ---------- fallback-path kernels ----------
__global__ void finalize_kernel(const float* __restrict__ row_sum, const float* __restrict__ copyg,
                                float* __restrict__ sscale) {
  unsigned r = blockIdx.x * blockDim.x + threadIdx.x;
  if (r < M_ROWS) sscale[r] = (1.f - copyg[r]) / row_sum[r];
}

__global__ void scale_kernel(float4* __restrict__ out, const float* __restrict__ sscale) {
  const unsigned total = M_ROWS * (N_VOCAB / 4);
  unsigned stride = gridDim.x * blockDim.x;
  for (unsigned i = blockIdx.x * blockDim.x + threadIdx.x; i < total; i += stride) {
    unsigned r = i / (N_VOCAB / 4);
    unsigned c = i % (N_VOCAB / 4);
    float s = sscale[r];
    float4 v = out[(size_t)r * (OUT_PITCH / 4) + c];
    v.x *= s; v.y *= s; v.z *= s; v.w *= s;
    out[(size_t)r * (OUT_PITCH / 4) + c] = v;
  }
}

__global__ void copyprob_kernel(const float* __restrict__ attn, const int* __restrict__ src_ids,
                                const float* __restrict__ copyg, float* __restrict__ out) {
  unsigned r = blockIdx.x;
  unsigned tid = threadIdx.x;
  __shared__ float cp[CV_DIM];
  for (unsigned v = tid; v < CV_DIM; v += 128) cp[v] = 0.f;
  __syncthreads();
  unsigned batch = r >> 7;
  float g = copyg[r];
  for (unsigned s = tid; s < S_DIM; s += 128) {
    float a = attn[(size_t)r * S_DIM + s] * g;
    atomicAdd(&cp[src_ids[batch * S_DIM + s]], a);
  }
  __syncthreads();
  for (unsigned v = tid; v < CV_DIM; v += 128)
    out[(size_t)r * OUT_PITCH + N_VOCAB + v] = cp[v];
}

extern "C" void kernel_launch(void* const* d_in, const int* in_sizes, int n_in,
                              void* d_out, int out_size, void* d_ws, size_t ws_size,
                              hipStream_t stream) {
  const float* hidden    = (const float*)d_in[0];
  const float* copy_attn = (const float*)d_in[1];
  const float* src_map   = (const float*)d_in[2];
  const float* W         = (const float*)d_in[3];
  const float* bias      = (const float*)d_in[4];
  const float* w_copy    = (const float*)d_in[5];
  const float* b_copy    = (const float*)d_in[6];
  float* out = (float*)d_out;

  char* ws = (char*)d_ws;
  unsigned char* W8 = (unsigned char*)(ws + W8_OFF);
  unsigned char* H8 = (unsigned char*)(ws + H8_OFF);
  float* copyg   = (float*)(ws + COPYG_OFF);
  float* row_sum = (float*)(ws + RSUM_OFF);
  float* sscale  = (float*)(ws + SSCALE_OFF);
  int*   src_ids = (int*)(ws + SRCID_OFF);
  unsigned short* Eb = (unsigned short*)(ws + EB_OFF);

  const bool bf16_path = (ws_size >= WS_NEED);

  cvt8_kernel<<<2048, 256, 0, stream>>>((const float4*)W, (unsigned*)W8,
                                        (unsigned)(N_VOCAB * K_DIM / 4));
  copygate_cvt_kernel<<<M_ROWS / 4, 256, 0, stream>>>(hidden, w_copy, b_copy, copyg, H8);
  srcids_kernel<<<(32 * S_DIM) / 4, 256, 0, stream>>>(src_map, src_ids);

  // main GEMM: 16 x 250 tiles of 256x128, 512 threads, 2 blocks/CU
  if (bf16_path) {
    gemm_exp_kernel<1><<<(M_ROWS / 256) * (N_VOCAB / 128), 512, 0, stream>>>(
        H8, W8, bias, out, Eb, row_sum);
    norm_scale_copy_kernel<<<M_ROWS, 256, 0, stream>>>(Eb, copyg, copy_attn, src_ids, out);
  } else {
    hipMemsetAsync(row_sum, 0, M_ROWS * sizeof(float), stream);
    gemm_exp_kernel<0><<<(M_ROWS / 256) * (N_VOCAB / 128), 512, 0, stream>>>(
        H8, W8, bias, out, Eb, row_sum);
    finalize_kernel<<<(M_ROWS + 255) / 256, 256, 0, stream>>>(row_sum, copyg, sscale);
    scale_kernel<<<4096, 256, 0, stream>>>((float4*)out, sscale);
    copyprob_kernel<<<M_ROWS, 128, 0, stream>>>(copy_attn, src_ids, copyg, out);
  }
}

// Round 17
// 359.945 us; speedup vs baseline: 1.1073x; 1.0125x over previous
//
#include <hip/hip_runtime.h>
#include <hip/hip_bf16.h>
#include <hip/hip_fp8.h>
#include <cstdint>
#include <cstddef>

// Problem dims
#define M_ROWS   4096     // B*T
#define N_VOCAB  32000    // V
#define K_DIM    512      // D
#define S_DIM    400
#define CV_DIM   600
#define OUT_PITCH 32600   // V + CV
#define PAD_IDX  1

typedef __attribute__((ext_vector_type(8))) short short8;
typedef __attribute__((ext_vector_type(8))) unsigned short ushort8;
typedef __attribute__((ext_vector_type(4))) float f32x4;
typedef long long i64;

// ws layout (fp8 inputs + bf16 exp intermediate) — R13 layout
#define W8_OFF   0ull                        // W fp8: 16,384,000 B
#define H8_OFF   16384000ull                 // hidden fp8: 2,097,152 B
#define COPYG_OFF 18481152ull
#define RSUM_OFF  18497536ull
#define SSCALE_OFF 18513920ull
#define SRCID_OFF 18530304ull                // 51,200 B
#define EB_OFF    18581504ull                // bf16 exp intermediate: 262,144,000 B
#define WS_NEED   (EB_OFF + 262144000ull)

__device__ inline void gload_lds16(const void* g, void* l) {
  __builtin_amdgcn_global_load_lds(
      (const __attribute__((address_space(1))) unsigned int*)g,
      (__attribute__((address_space(3))) unsigned int*)l, 16, 0, 0);
}

__device__ inline unsigned short f32_to_bf16_rn(float f) {
  unsigned u = __float_as_uint(f);
  u += 0x7FFFu + ((u >> 16) & 1u);
  return (unsigned short)(u >> 16);
}
__device__ inline float bf16_to_f32(unsigned short h) {
  return __uint_as_float((unsigned)h << 16);
}
__device__ inline unsigned f32_to_fp8(float f) {
  __hip_fp8_e4m3 q(f);
  return (unsigned)(unsigned char)q.__x;
}

// ---------- K1: merged prelude (one launch, 3 independent jobs) ----------
// blocks [0,2048): W fp32->fp8 grid-stride
// blocks [2048,3072): copy gate + hidden->fp8 (4 rows/block, 1 wave/row)
// blocks [3072,6272): src_ids recovery (4 positions/block, 1 wave/pos)
#define PRELUDE_BLOCKS (2048 + 1024 + 3200)
__global__ void prelude_kernel(const float4* __restrict__ W4, unsigned* __restrict__ W8out,
                               const float* __restrict__ hidden,
                               const float* __restrict__ w_copy,
                               const float* __restrict__ b_copy,
                               float* __restrict__ copyg,
                               unsigned char* __restrict__ H8,
                               const float* __restrict__ src_map,
                               int* __restrict__ src_ids) {
  unsigned b = blockIdx.x;
  if (b < 2048u) {
    const unsigned n4 = N_VOCAB * K_DIM / 4;           // 4,096,000
    for (unsigned i = b * 256u + threadIdx.x; i < n4; i += 2048u * 256u) {
      float4 v = W4[i];
      W8out[i] = f32_to_fp8(v.x) | (f32_to_fp8(v.y) << 8)
               | (f32_to_fp8(v.z) << 16) | (f32_to_fp8(v.w) << 24);
    }
  } else if (b < 3072u) {
    unsigned gw = (b - 2048u) * 4u + (threadIdx.x >> 6);   // row
    unsigned lane = threadIdx.x & 63u;
    if (gw >= M_ROWS) return;
    const float4* h4 = (const float4*)(hidden + (size_t)gw * K_DIM);
    const float4* w4 = (const float4*)w_copy;
    float4 a0 = h4[lane * 2 + 0], w0 = w4[lane * 2 + 0];
    float4 a1 = h4[lane * 2 + 1], w1 = w4[lane * 2 + 1];
    float dot = a0.x * w0.x + a0.y * w0.y + a0.z * w0.z + a0.w * w0.w
              + a1.x * w1.x + a1.y * w1.y + a1.z * w1.z + a1.w * w1.w;
    unsigned lo = f32_to_fp8(a0.x) | (f32_to_fp8(a0.y) << 8)
                | (f32_to_fp8(a0.z) << 16) | (f32_to_fp8(a0.w) << 24);
    unsigned hi = f32_to_fp8(a1.x) | (f32_to_fp8(a1.y) << 8)
                | (f32_to_fp8(a1.z) << 16) | (f32_to_fp8(a1.w) << 24);
    uint2 pk; pk.x = lo; pk.y = hi;
    *(uint2*)(H8 + (size_t)gw * K_DIM + lane * 8u) = pk;
    #pragma unroll
    for (int mask = 1; mask < 64; mask <<= 1) dot += __shfl_xor(dot, mask);
    if (lane == 0) copyg[gw] = 1.f / (1.f + __expf(-(dot + b_copy[0])));
  } else {
    unsigned pos = (b - 3072u) * 4u + (threadIdx.x >> 6);   // b*S + s
    unsigned lane = threadIdx.x & 63u;
    if (pos >= 32 * S_DIM) return;
    const float* row = src_map + (size_t)pos * CV_DIM;
    int found = 1 << 30;
    for (int v = lane; v < CV_DIM; v += 64)
      if (row[v] > 0.5f) found = v;
    #pragma unroll
    for (int mask = 1; mask < 64; mask <<= 1) {
      int o = __shfl_xor(found, mask);
      found = found < o ? found : o;
    }
    if (lane == 0) src_ids[pos] = found;
  }
}

// ---------- K2: 256x128 fp8 MFMA GEMM, BK=128 + exp epilogue (bf16 out) ----------
// R13 structure (byte-for-byte): 8 waves (4M x 2N), 64x64/wave, BK=128 ->
// 4 K-steps, 48 KB LDS, XOR-(row&7) swizzle, 2 blocks/CU, reuse-aware XCD
// map, swapped operands -> register-direct ushort4 bf16 stores.
template<int BF16OUT>
__global__ __launch_bounds__(512, 2)
void gemm_exp_kernel(const unsigned char* __restrict__ A,
                     const unsigned char* __restrict__ B,
                     const float* __restrict__ bias,
                     float* __restrict__ out,
                     unsigned short* __restrict__ Eb,
                     float* __restrict__ row_sum) {
  __shared__ unsigned char smem[49152];      // As 32 KB | Bs 16 KB
  unsigned char* As = smem;
  unsigned char* Bs = smem + 32768;

  unsigned bid = blockIdx.x;
  // reuse-aware bijective map over 4000 blocks (16 mt x 250 nt)
  unsigned xcd = bid & 7u, local = bid >> 3;      // local 0..499
  unsigned slab = xcd >> 1, half = xcd & 1u;
  unsigned nt = half * 125u + (local >> 2);
  unsigned mt = slab * 4u + (local & 3u);
  unsigned m0 = mt * 256u, n0 = nt * 128u;

  unsigned tid = threadIdx.x;
  unsigned lane = tid & 63u;
  unsigned wid = tid >> 6;
  unsigned wm = wid >> 1, wn = wid & 1u;     // 4 x 2 wave grid, 64x64 per wave
  unsigned lr = lane >> 4, lc = lane & 15u;

  // staging: A 2048 16B-units, B 1024; unit u -> row u>>3, lds chunk u&7,
  // source chunk (u&7)^(row&7). Row = 128 fp8 = 128 B.
  const unsigned char* Asrc[4];
  const unsigned char* Bsrc[2];
  unsigned dstA[4], dstB[2];
  #pragma unroll
  for (unsigned i = 0; i < 4; ++i) {
    unsigned u = i * 512u + tid;
    unsigned rr = u >> 3;                        // 0..255
    unsigned ch = (u & 7u) ^ (rr & 7u);
    dstA[i] = u * 16u;
    Asrc[i] = A + (size_t)(m0 + rr) * K_DIM + ch * 16u;
  }
  #pragma unroll
  for (unsigned i = 0; i < 2; ++i) {
    unsigned u = i * 512u + tid;
    unsigned rr = u >> 3;                        // 0..127
    unsigned ch = (u & 7u) ^ (rr & 7u);
    dstB[i] = u * 16u;
    Bsrc[i] = B + (size_t)(n0 + rr) * K_DIM + ch * 16u;
  }
  // fragment read bases: row byte base + swizzle key
  unsigned abase[4], akey[4], bbase[4], bkey[4];
  #pragma unroll
  for (int m = 0; m < 4; ++m) {
    unsigned r = wm * 64u + m * 16u + lc;
    abase[m] = r * 128u; akey[m] = r & 7u;
  }
  #pragma unroll
  for (int n = 0; n < 4; ++n) {
    unsigned r = wn * 64u + n * 16u + lc;
    bbase[n] = r * 128u; bkey[n] = r & 7u;
  }
  const unsigned hsel = (lr & 1u) * 8u;          // 8B half within 16B chunk

  f32x4 acc[4][4] = {};

  for (unsigned kt = 0; kt < 4; ++kt) {          // BK=128: 4 K-steps only
    unsigned k0 = kt * 128u;
    #pragma unroll
    for (unsigned i = 0; i < 4; ++i)
      gload_lds16(Asrc[i] + k0, As + dstA[i]);
    #pragma unroll
    for (unsigned i = 0; i < 2; ++i)
      gload_lds16(Bsrc[i] + k0, Bs + dstB[i]);
    __syncthreads();   // compiler emits vmcnt(0) drain before barrier
    #pragma unroll
    for (unsigned ks = 0; ks < 4; ++ks) {        // k = ks*32 .. +32
      unsigned h = ks * 2u + (lr >> 1);          // 16B chunk index 0..7
      i64 av[4], bv[4];
      #pragma unroll
      for (int m = 0; m < 4; ++m)
        av[m] = *(const i64*)(As + abase[m] + ((h ^ akey[m]) * 16u) + hsel);
      #pragma unroll
      for (int n = 0; n < 4; ++n)
        bv[n] = *(const i64*)(Bs + bbase[n] + ((h ^ bkey[n]) * 16u) + hsel);
      #pragma unroll
      for (int m = 0; m < 4; ++m)
        #pragma unroll
        for (int n = 0; n < 4; ++n)
          acc[m][n] = __builtin_amdgcn_mfma_f32_16x16x32_fp8_fp8(bv[n], av[m],
                                                                 acc[m][n], 0, 0, 0);
    }
    __syncthreads();
  }

  // epilogue: acc[m][n][j] = logit(row = m0+wm*64+m*16+lc, col = n0+wn*64+n*16+lr*4+j)
  float4 bv4[4];
  #pragma unroll
  for (int n = 0; n < 4; ++n)
    bv4[n] = *(const float4*)&bias[n0 + wn * 64u + n * 16u + lr * 4u];

  if (BF16OUT) {
    #pragma unroll
    for (int m = 0; m < 4; ++m) {
      unsigned grow = m0 + wm * 64u + m * 16u + lc;
      unsigned short* rowp = Eb + (size_t)grow * N_VOCAB;
      #pragma unroll
      for (int n = 0; n < 4; ++n) {
        unsigned gcol = n0 + wn * 64u + n * 16u + lr * 4u;
        float e0 = (gcol + 0u == PAD_IDX) ? 0.f : __expf(acc[m][n][0] + bv4[n].x);
        float e1 = (gcol + 1u == PAD_IDX) ? 0.f : __expf(acc[m][n][1] + bv4[n].y);
        float e2 = (gcol + 2u == PAD_IDX) ? 0.f : __expf(acc[m][n][2] + bv4[n].z);
        float e3 = (gcol + 3u == PAD_IDX) ? 0.f : __expf(acc[m][n][3] + bv4[n].w);
        ushort4 o;
        o.x = f32_to_bf16_rn(e0); o.y = f32_to_bf16_rn(e1);
        o.z = f32_to_bf16_rn(e2); o.w = f32_to_bf16_rn(e3);
        *(ushort4*)(rowp + gcol) = o;
      }
    }
  } else {
    // fallback: fp32 float4 stores + atomic row sums
    #pragma unroll
    for (int m = 0; m < 4; ++m) {
      unsigned grow = m0 + wm * 64u + m * 16u + lc;
      float rs = 0.f;
      #pragma unroll
      for (int n = 0; n < 4; ++n) {
        unsigned gcol = n0 + wn * 64u + n * 16u + lr * 4u;
        float4 e;
        e.x = (gcol + 0u == PAD_IDX) ? 0.f : __expf(acc[m][n][0] + bv4[n].x);
        e.y = (gcol + 1u == PAD_IDX) ? 0.f : __expf(acc[m][n][1] + bv4[n].y);
        e.z = (gcol + 2u == PAD_IDX) ? 0.f : __expf(acc[m][n][2] + bv4[n].z);
        e.w = (gcol + 3u == PAD_IDX) ? 0.f : __expf(acc[m][n][3] + bv4[n].w);
        *(float4*)(out + (size_t)grow * OUT_PITCH + gcol) = e;
        rs += e.x + e.y + e.z + e.w;
      }
      rs += __shfl_xor(rs, 16);
      rs += __shfl_xor(rs, 32);
      if (lr == 0) atomicAdd(&row_sum[grow], rs);
    }
  }
}

// ---------- K3: fused per-row sum + scale + copy-branch scatter ----------
// (R15/R16-proven.) One block per row. Row (62.5 KB bf16) to registers,
// block-reduce sum, scale+store fp32 main region; copy branch scattered via
// LDS into the same row's extended-vocab region. No global atomics.
__global__ __launch_bounds__(256)
void norm_scale_copy_kernel(const unsigned short* __restrict__ Eb,
                            const float* __restrict__ copyg,
                            const float* __restrict__ attn,
                            const int* __restrict__ src_ids,
                            float* __restrict__ out) {
  unsigned r = blockIdx.x;
  unsigned tid = threadIdx.x;
  __shared__ float cp[CV_DIM];
  __shared__ float wsum[4];
  for (unsigned v2 = tid; v2 < CV_DIM; v2 += 256) cp[v2] = 0.f;

  const ushort8* src = (const ushort8*)(Eb + (size_t)r * N_VOCAB);   // 4000 chunks
  ushort8 v[16];
  float lsum = 0.f;
  #pragma unroll
  for (int i = 0; i < 16; ++i) {
    unsigned c = (unsigned)i * 256u + tid;
    if (c < 4000u) {
      v[i] = src[c];
      #pragma unroll
      for (int k = 0; k < 8; ++k) lsum += bf16_to_f32(v[i][k]);
    }
  }
  #pragma unroll
  for (int mask = 1; mask < 64; mask <<= 1) lsum += __shfl_xor(lsum, mask);
  if ((tid & 63u) == 0) wsum[tid >> 6] = lsum;
  __syncthreads();                 // wsum ready; cp zeroed

  float g = copyg[r];
  float s = (1.f - g) / (wsum[0] + wsum[1] + wsum[2] + wsum[3]);

  // copy-branch scatter into LDS (row's batch shares src_ids)
  unsigned batch = r >> 7;
  for (unsigned sp = tid; sp < S_DIM; sp += 256) {
    float a = attn[(size_t)r * S_DIM + sp] * g;
    atomicAdd(&cp[src_ids[batch * S_DIM + sp]], a);
  }

  // main region scale + store (from registers)
  float* dst = out + (size_t)r * OUT_PITCH;
  #pragma unroll
  for (int i = 0; i < 16; ++i) {
    unsigned c = (unsigned)i * 256u + tid;
    if (c < 4000u) {
      float4 lo, hi;
      lo.x = bf16_to_f32(v[i][0]) * s; lo.y = bf16_to_f32(v[i][1]) * s;
      lo.z = bf16_to_f32(v[i][2]) * s; lo.w = bf16_to_f32(v[i][3]) * s;
      hi.x = bf16_to_f32(v[i][4]) * s; hi.y = bf16_to_f32(v[i][5]) * s;
      hi.z = bf16_to_f32(v[i][6]) * s; hi.w = bf16_to_f32(v[i][7]) * s;
      float4* o = (float4*)(dst + c * 8u);
      o[0] = lo; o[1] = hi;
    }
  }
  __syncthreads();                 // scatter complete
  for (unsigned v2 = tid; v2 < CV_DIM; v2 += 256)
    dst[N_VOCAB + v2] = cp[v2];
}

// ---------- fallback-path kernels ----------
__global__ void finalize_kernel(const float* __restrict__ row_sum, const float* __restrict__ copyg,
                                float* __restrict__ sscale) {
  unsigned r = blockIdx.x * blockDim.x + threadIdx.x;
  if (r < M_ROWS) sscale[r] = (1.f - copyg[r]) / row_sum[r];
}

__global__ void scale_kernel(float4* __restrict__ out, const float* __restrict__ sscale) {
  const unsigned total = M_ROWS * (N_VOCAB / 4);
  unsigned stride = gridDim.x * blockDim.x;
  for (unsigned i = blockIdx.x * blockDim.x + threadIdx.x; i < total; i += stride) {
    unsigned r = i / (N_VOCAB / 4);
    unsigned c = i % (N_VOCAB / 4);
    float s = sscale[r];
    float4 v = out[(size_t)r * (OUT_PITCH / 4) + c];
    v.x *= s; v.y *= s; v.z *= s; v.w *= s;
    out[(size_t)r * (OUT_PITCH / 4) + c] = v;
  }
}

__global__ void copyprob_kernel(const float* __restrict__ attn, const int* __restrict__ src_ids,
                                const float* __restrict__ copyg, float* __restrict__ out) {
  unsigned r = blockIdx.x;
  unsigned tid = threadIdx.x;
  __shared__ float cp[CV_DIM];
  for (unsigned v = tid; v < CV_DIM; v += 128) cp[v] = 0.f;
  __syncthreads();
  unsigned batch = r >> 7;
  float g = copyg[r];
  for (unsigned s = tid; s < S_DIM; s += 128) {
    float a = attn[(size_t)r * S_DIM + s] * g;
    atomicAdd(&cp[src_ids[batch * S_DIM + s]], a);
  }
  __syncthreads();
  for (unsigned v = tid; v < CV_DIM; v += 128)
    out[(size_t)r * OUT_PITCH + N_VOCAB + v] = cp[v];
}

extern "C" void kernel_launch(void* const* d_in, const int* in_sizes, int n_in,
                              void* d_out, int out_size, void* d_ws, size_t ws_size,
                              hipStream_t stream) {
  const float* hidden    = (const float*)d_in[0];
  const float* copy_attn = (const float*)d_in[1];
  const float* src_map   = (const float*)d_in[2];
  const float* W         = (const float*)d_in[3];
  const float* bias      = (const float*)d_in[4];
  const float* w_copy    = (const float*)d_in[5];
  const float* b_copy    = (const float*)d_in[6];
  float* out = (float*)d_out;

  char* ws = (char*)d_ws;
  unsigned char* W8 = (unsigned char*)(ws + W8_OFF);
  unsigned char* H8 = (unsigned char*)(ws + H8_OFF);
  float* copyg   = (float*)(ws + COPYG_OFF);
  float* row_sum = (float*)(ws + RSUM_OFF);
  float* sscale  = (float*)(ws + SSCALE_OFF);
  int*   src_ids = (int*)(ws + SRCID_OFF);
  unsigned short* Eb = (unsigned short*)(ws + EB_OFF);

  const bool bf16_path = (ws_size >= WS_NEED);

  prelude_kernel<<<PRELUDE_BLOCKS, 256, 0, stream>>>(
      (const float4*)W, (unsigned*)W8, hidden, w_copy, b_copy, copyg, H8,
      src_map, src_ids);

  // main GEMM: 16 x 250 tiles of 256x128, 512 threads, 2 blocks/CU
  if (bf16_path) {
    gemm_exp_kernel<1><<<(M_ROWS / 256) * (N_VOCAB / 128), 512, 0, stream>>>(
        H8, W8, bias, out, Eb, row_sum);
    norm_scale_copy_kernel<<<M_ROWS, 256, 0, stream>>>(Eb, copyg, copy_attn, src_ids, out);
  } else {
    hipMemsetAsync(row_sum, 0, M_ROWS * sizeof(float), stream);
    gemm_exp_kernel<0><<<(M_ROWS / 256) * (N_VOCAB / 128), 512, 0, stream>>>(
        H8, W8, bias, out, Eb, row_sum);
    finalize_kernel<<<(M_ROWS + 255) / 256, 256, 0, stream>>>(row_sum, copyg, sscale);
    scale_kernel<<<4096, 256, 0, stream>>>((float4*)out, sscale);
    copyprob_kernel<<<M_ROWS, 128, 0, stream>>>(copy_attn, src_ids, copyg, out);
  }
}